// Round 1
// baseline (52.477 us; speedup 1.0000x reference)
//
#include <hip/hip_runtime.h>
#include <hip/hip_bf16.h>

// PIXOR feature layer:
//   intensity[n] = mean_t vox_feats[n, t, 4]
//   out[b, 0, y, x] = 1.0   (occupancy, any voxel mapping there)
//   out[b, 1, y, x] = intensity[n_last]  (last duplicate wins == max n wins)
// Grid: NY=800, NX=700, B = out_size / (2*NY*NX)

#define PX_NY 800
#define PX_NX 700
#define PX_T  32
#define PX_C  5

// Kernel B: compute per-voxel intensity, and atomicMax the voxel index (n+1)
// into the intensity plane of the output (viewed as int). Plane was zeroed,
// and 0 == empty; winners hold max(n)+1.
__global__ void __launch_bounds__(256)
pixor_intens_vote(const float* __restrict__ vox,
                  const int*   __restrict__ coords,
                  float*       __restrict__ intens,
                  int*         __restrict__ out_i,
                  int N, int P /* NY*NX */) {
    int n = blockIdx.x * blockDim.x + threadIdx.x;
    if (n >= N) return;

    // channel-4 elements of row n: vox[n*160 + t*5 + 4]
    const float* row = vox + (size_t)n * (PX_T * PX_C) + (PX_C - 1);
    float s = 0.0f;
#pragma unroll
    for (int t = 0; t < PX_T; ++t) {
        s += row[t * PX_C];
    }
    intens[n] = s * (1.0f / (float)PX_T);

    int4 c = ((const int4*)coords)[n];      // (b, z, y, x)
    int cell = c.x * (2 * P) + P + c.z * PX_NX + c.w;  // intensity plane
    atomicMax(out_i + cell, n + 1);
}

// Kernel C: write occupancy; the winning voxel replaces its vote (n+1) with
// its float intensity. Empty cells keep int 0 == float +0.0.
__global__ void __launch_bounds__(256)
pixor_finalize(const int*   __restrict__ coords,
               const float* __restrict__ intens,
               float*       __restrict__ out,
               int N, int P) {
    int n = blockIdx.x * blockDim.x + threadIdx.x;
    if (n >= N) return;

    int4 c = ((const int4*)coords)[n];
    int base = c.x * (2 * P) + c.z * PX_NX + c.w;

    out[base] = 1.0f;                        // occupancy plane (all write 1.0)

    int* ip = (int*)out + base + P;          // intensity plane cell
    if (*ip == n + 1) {
        *(float*)ip = intens[n];
    }
}

extern "C" void kernel_launch(void* const* d_in, const int* in_sizes, int n_in,
                              void* d_out, int out_size, void* d_ws, size_t ws_size,
                              hipStream_t stream) {
    const float* vox    = (const float*)d_in[0];   // [N, 32, 5] f32
    const int*   coords = (const int*)d_in[2];     // [N, 4] i32 (b, z, y, x)
    // d_in[1] (num_points) unused by the reference; d_in[3] (batch_size) is
    // recoverable from out_size.
    float* out = (float*)d_out;

    const int N = in_sizes[1];                     // 200000
    const int P = PX_NY * PX_NX;                   // 560000

    float* ws_int = (float*)d_ws;                  // N floats of scratch

    // Zero the whole output: occ plane needs 0 background; intensity plane
    // doubles as the int voting buffer (0 == empty == float +0.0).
    hipMemsetAsync(d_out, 0, (size_t)out_size * sizeof(float), stream);

    const int BLK = 256;
    const int grid = (N + BLK - 1) / BLK;

    pixor_intens_vote<<<grid, BLK, 0, stream>>>(vox, coords, ws_int, (int*)out, N, P);
    pixor_finalize  <<<grid, BLK, 0, stream>>>(coords, ws_int, out, N, P);
}